// Round 1
// baseline (169.710 us; speedup 1.0000x reference)
//
#include <hip/hip_runtime.h>
#include <math.h>

#define PI_F 3.14159265358979323846f

// ---------------- batched tiled f32 GEMM: C = A @ W + bias ----------------
struct GemmArgs {
    const float* A[4];
    const float* W[4];
    const float* bias[4];
    float* C[4];
};

#define BM 64
#define BN 64
#define BKK 16

__global__ __launch_bounds__(256) void gemm_f32(GemmArgs args, int M, int N, int K) {
    const int zb = blockIdx.z;
    const float* __restrict__ A = args.A[zb];
    const float* __restrict__ W = args.W[zb];
    const float* __restrict__ bias = args.bias[zb];
    float* __restrict__ C = args.C[zb];

    const int m0 = blockIdx.y * BM;
    const int n0 = blockIdx.x * BN;

    __shared__ float As[BKK][BM];
    __shared__ float Bs[BKK][BN];

    const int tid = threadIdx.x;
    const int tx = tid & 15;   // n dir
    const int ty = tid >> 4;   // m dir

    float acc[4][4] = {};

    for (int k0 = 0; k0 < K; k0 += BKK) {
#pragma unroll
        for (int i = 0; i < 4; i++) {
            int idx = tid + i * 256;
            int r = idx >> 4, c = idx & 15;
            As[c][r] = A[(m0 + r) * K + k0 + c];
        }
#pragma unroll
        for (int i = 0; i < 4; i++) {
            int idx = tid + i * 256;
            int r = idx >> 6, c = idx & 63;
            Bs[r][c] = W[(k0 + r) * N + n0 + c];
        }
        __syncthreads();
#pragma unroll
        for (int kk = 0; kk < BKK; kk++) {
            float a_[4], b_[4];
#pragma unroll
            for (int i = 0; i < 4; i++) a_[i] = As[kk][ty * 4 + i];
#pragma unroll
            for (int j = 0; j < 4; j++) b_[j] = Bs[kk][tx * 4 + j];
#pragma unroll
            for (int i = 0; i < 4; i++)
#pragma unroll
                for (int j = 0; j < 4; j++) acc[i][j] += a_[i] * b_[j];
        }
        __syncthreads();
    }

#pragma unroll
    for (int i = 0; i < 4; i++) {
        int row = m0 + ty * 4 + i;
#pragma unroll
        for (int j = 0; j < 4; j++) {
            int col = n0 + tx * 4 + j;
            C[row * N + col] = acc[i][j] + bias[col];
        }
    }
}

// ---------------- per-token quantum scalar path ----------------
// fa8[c] = (Xa_row . We[:,c]) + be[c]; pa = prod cos(fa8*pi/2); same for visual.
// e = (pa/(|pa|+1e-10)) * (pv/(|pv|+1e-10)); two nonzero ent entries = 0.7071*e.
__global__ __launch_bounds__(64) void token_scalars(const float* __restrict__ xa,
                                                    const float* __restrict__ xv,
                                                    const float* __restrict__ We,
                                                    const float* __restrict__ be,
                                                    float* __restrict__ scale,
                                                    float* __restrict__ coh_tok,
                                                    float* __restrict__ ent_tok) {
    const int t = blockIdx.x;      // 0..511  (b*256+s)
    const int lane = threadIdx.x;  // 0..63

    __shared__ __align__(16) float xs[2][512];
    const float4* xaRow = (const float4*)(xa + t * 512);
    const float4* xvRow = (const float4*)(xv + t * 512);
#pragma unroll
    for (int i = lane; i < 128; i += 64) {
        ((float4*)xs[0])[i] = xaRow[i];
        ((float4*)xs[1])[i] = xvRow[i];
    }
    __syncthreads();

    float accA[8] = {}, accV[8] = {};
#pragma unroll
    for (int i = 0; i < 8; i++) {
        int k = i * 64 + lane;
        float wa = xs[0][k], wv = xs[1][k];
        const float* wrow = &We[k * 512];
#pragma unroll
        for (int c = 0; c < 8; c++) {
            float w = wrow[c];
            accA[c] += wa * w;
            accV[c] += wv * w;
        }
    }
#pragma unroll
    for (int c = 0; c < 8; c++) {
#pragma unroll
        for (int o = 32; o >= 1; o >>= 1) {
            accA[c] += __shfl_xor(accA[c], o);
            accV[c] += __shfl_xor(accV[c], o);
        }
    }
    if (lane == 0) {
        float pa = 1.f, pv = 1.f;
#pragma unroll
        for (int c = 0; c < 8; c++) {
            pa *= cosf((accA[c] + be[c]) * (PI_F * 0.5f));
            pv *= cosf((accV[c] + be[c]) * (PI_F * 0.5f));
        }
        float s0a = pa / (fabsf(pa) + 1e-10f);
        float s0v = pv / (fabsf(pv) + 1e-10f);
        float e = s0a * s0v;
        const float a = 0.7071f;
        float ent0 = a * e;
        float qsum = 2.f * ent0 * ent0;
        float interf = (ent0 < 0.f) ? cosf(2.f * PI_F / 65536.f) : 1.f;
        scale[t] = qsum * interf;
        coh_tok[t] = 2.f * fabsf(ent0);
        float p = (ent0 * ent0) / (qsum + 1e-10f);
        ent_tok[t] = -2.f * p * logf(p + 1e-10f);
    }
}

// ---------------- attention: logits + softmax, one block per (b,h,q) ----------------
__global__ __launch_bounds__(256) void attn_softmax(const float* __restrict__ aq,
                                                    const float* __restrict__ vk,
                                                    const float* __restrict__ scale,
                                                    float* __restrict__ attn,
                                                    float* __restrict__ attn_last) {
    const int q = blockIdx.x, h = blockIdx.y, b = blockIdx.z;
    const int k = threadIdx.x;

    __shared__ __align__(16) float qrow[64];
    __shared__ float redm[4], reds[4];

    if (k < 64) qrow[k] = aq[(b * 256 + q) * 512 + h * 64 + k];
    __syncthreads();

    const float* vrow = &vk[(b * 256 + k) * 512 + h * 64];
    float dot = 0.f;
#pragma unroll
    for (int j = 0; j < 64; j += 4) {
        float4 v = *(const float4*)(vrow + j);
        float4 qv = *(const float4*)(qrow + j);
        dot += v.x * qv.x + v.y * qv.y + v.z * qv.z + v.w * qv.w;
    }
    float logit = dot * scale[b * 256 + q] * 0.125f;

    const int wid = k >> 6, lane = k & 63;
    float m = logit;
#pragma unroll
    for (int o = 32; o >= 1; o >>= 1) m = fmaxf(m, __shfl_xor(m, o));
    if (lane == 0) redm[wid] = m;
    __syncthreads();
    m = fmaxf(fmaxf(redm[0], redm[1]), fmaxf(redm[2], redm[3]));

    float ex = expf(logit - m);
    float s = ex;
#pragma unroll
    for (int o = 32; o >= 1; o >>= 1) s += __shfl_xor(s, o);
    if (lane == 0) reds[wid] = s;
    __syncthreads();
    s = reds[0] + reds[1] + reds[2] + reds[3];

    float p = ex / s;
    attn[((b * 8 + h) * 256 + q) * 256 + k] = p;
    if (h == 7) attn_last[(b * 256 + q) * 256 + k] = p;
}

// ---------------- audio_att[b,q,h*64+d] = sum_k attn[b,h,q,k] * vv[b,k,h*64+d] ----------------
__global__ __launch_bounds__(64) void av_audio(const float* __restrict__ attn,
                                               const float* __restrict__ vv,
                                               float* __restrict__ out) {
    const int q = blockIdx.x, h = blockIdx.y, b = blockIdx.z, d = threadIdx.x;
    __shared__ __align__(16) float arow[256];
    const float4* ap = (const float4*)&attn[((b * 8 + h) * 256 + q) * 256];
    ((float4*)arow)[d] = ap[d];
    __syncthreads();
    float acc = 0.f;
    const float* vbase = &vv[b * 256 * 512 + h * 64 + d];
#pragma unroll 4
    for (int k = 0; k < 256; k++) acc += arow[k] * vbase[k * 512];
    out[(b * 256 + q) * 512 + h * 64 + d] = acc;
}

// ---------------- visual_att[b,k,h*64+d] = sum_q attn[b,h,q,k] * av[b,q,h*64+d] ----------------
__global__ __launch_bounds__(64) void av_visual(const float* __restrict__ attn,
                                                const float* __restrict__ av,
                                                float* __restrict__ out) {
    const int kk = blockIdx.x, h = blockIdx.y, b = blockIdx.z, d = threadIdx.x;
    __shared__ float acol[256];
    for (int i = d; i < 256; i += 64) acol[i] = attn[((b * 8 + h) * 256 + i) * 256 + kk];
    __syncthreads();
    float acc = 0.f;
    const float* abase = &av[b * 256 * 512 + h * 64 + d];
#pragma unroll 4
    for (int q = 0; q < 256; q++) acc += acol[q] * abase[q * 512];
    out[(b * 256 + kk) * 512 + h * 64 + d] = acc;
}

// ---------------- residual + LayerNorm, one block per token (1024 tokens) ----------------
__global__ __launch_bounds__(256) void ln_kernel(const float* __restrict__ xa,
                                                 const float* __restrict__ xv,
                                                 const float* __restrict__ proj,
                                                 const float* __restrict__ gamma,
                                                 const float* __restrict__ beta,
                                                 float* __restrict__ out) {
    const int t = blockIdx.x;  // 0..1023
    const int tid = threadIdx.x;
    const float* x = (t < 512) ? (xa + t * 512) : (xv + (t - 512) * 512);
    const float* p = proj + t * 512;

    float y0 = x[tid] + p[tid];
    float y1 = x[tid + 256] + p[tid + 256];

    __shared__ float red[4];
    const int wid = tid >> 6, lane = tid & 63;

    float s = y0 + y1;
#pragma unroll
    for (int o = 32; o >= 1; o >>= 1) s += __shfl_xor(s, o);
    if (lane == 0) red[wid] = s;
    __syncthreads();
    float mean = (red[0] + red[1] + red[2] + red[3]) * (1.f / 512.f);

    float d0 = y0 - mean, d1 = y1 - mean;
    float v = d0 * d0 + d1 * d1;
    __syncthreads();
#pragma unroll
    for (int o = 32; o >= 1; o >>= 1) v += __shfl_xor(v, o);
    if (lane == 0) red[wid] = v;
    __syncthreads();
    float var = (red[0] + red[1] + red[2] + red[3]) * (1.f / 512.f);
    float rstd = rsqrtf(var + 1e-5f);

    out[t * 512 + tid] = d0 * rstd * gamma[tid] + beta[tid];
    out[t * 512 + tid + 256] = d1 * rstd * gamma[tid + 256] + beta[tid + 256];
}

// ---------------- final scalar reduction ----------------
__global__ __launch_bounds__(512) void finalize_scalars(const float* __restrict__ coh,
                                                        const float* __restrict__ entt,
                                                        float* __restrict__ out) {
    const int tid = threadIdx.x;
    float c = coh[tid], e = entt[tid];
    const int wid = tid >> 6, lane = tid & 63;
    __shared__ float rc[8], re[8];
#pragma unroll
    for (int o = 32; o >= 1; o >>= 1) {
        c += __shfl_xor(c, o);
        e += __shfl_xor(e, o);
    }
    if (lane == 0) { rc[wid] = c; re[wid] = e; }
    __syncthreads();
    if (tid == 0) {
        float cs = 0.f, es = 0.f;
#pragma unroll
        for (int i = 0; i < 8; i++) { cs += rc[i]; es += re[i]; }
        out[524288] = cs / (512.f * 65536.f);
        out[524289] = es / 512.f;
    }
}

extern "C" void kernel_launch(void* const* d_in, const int* in_sizes, int n_in,
                              void* d_out, int out_size, void* d_ws, size_t ws_size,
                              hipStream_t stream) {
    const float* audio  = (const float*)d_in[0];
    const float* visual = (const float*)d_in[1];
    const float* Wq = (const float*)d_in[2];
    const float* bq = (const float*)d_in[3];
    const float* Wk = (const float*)d_in[4];
    const float* bk = (const float*)d_in[5];
    const float* Wv = (const float*)d_in[6];
    const float* bv = (const float*)d_in[7];
    const float* Wo = (const float*)d_in[8];
    const float* bo = (const float*)d_in[9];
    const float* We = (const float*)d_in[10];
    const float* be = (const float*)d_in[11];
    const float* gamma = (const float*)d_in[12];
    const float* beta  = (const float*)d_in[13];
    float* out = (float*)d_out;

    float* ws = (float*)d_ws;
    float* aq     = ws;                 // 262144
    float* vk     = ws + 262144;        // 262144
    float* vv     = ws + 524288;        // 262144
    float* av     = ws + 786432;        // 262144
    float* attcat = ws + 1048576;       // 524288 (audio_att | visual_att)
    float* proj   = ws + 1572864;       // 524288 (audio_out | visual_out)
    float* attn   = ws + 2097152;       // 1048576
    float* scale  = ws + 3145728;       // 512
    float* coh    = ws + 3146240;       // 512
    float* entt   = ws + 3146752;       // 512

    // 1) projections: aq = Xa@Wq+bq, vk = Xv@Wk+bk, vv = Xv@Wv+bv, av = Xa@Wv+bv
    GemmArgs g1;
    g1.A[0] = audio;  g1.W[0] = Wq; g1.bias[0] = bq; g1.C[0] = aq;
    g1.A[1] = visual; g1.W[1] = Wk; g1.bias[1] = bk; g1.C[1] = vk;
    g1.A[2] = visual; g1.W[2] = Wv; g1.bias[2] = bv; g1.C[2] = vv;
    g1.A[3] = audio;  g1.W[3] = Wv; g1.bias[3] = bv; g1.C[3] = av;
    hipLaunchKernelGGL(gemm_f32, dim3(8, 8, 4), dim3(256), 0, stream, g1, 512, 512, 512);

    // 2) per-token scalar path (scale, coherence, entropy contributions)
    hipLaunchKernelGGL(token_scalars, dim3(512), dim3(64), 0, stream,
                       audio, visual, We, be, scale, coh, entt);

    // 3) attention logits + softmax (+ write attn[:,7] to output)
    hipLaunchKernelGGL(attn_softmax, dim3(256, 8, 2), dim3(256), 0, stream,
                       aq, vk, scale, attn, out + 524290);

    // 4) audio_att = attn @ vv_heads
    hipLaunchKernelGGL(av_audio, dim3(256, 8, 2), dim3(64), 0, stream, attn, vv, attcat);

    // 5) visual_att = attn^T @ av_heads
    hipLaunchKernelGGL(av_visual, dim3(256, 8, 2), dim3(64), 0, stream, attn, av, attcat + 262144);

    // 6) output projection for both (concatenated rows): proj = attcat @ Wo + bo
    GemmArgs g2;
    for (int i = 0; i < 4; i++) { g2.A[i] = attcat; g2.W[i] = Wo; g2.bias[i] = bo; g2.C[i] = proj; }
    hipLaunchKernelGGL(gemm_f32, dim3(8, 16, 1), dim3(256), 0, stream, g2, 1024, 512, 512);

    // 7) residual + LN -> audio_final | visual_final
    hipLaunchKernelGGL(ln_kernel, dim3(1024), dim3(256), 0, stream,
                       audio, visual, proj, gamma, beta, out);

    // 8) scalars
    hipLaunchKernelGGL(finalize_scalars, dim3(1), dim3(512), 0, stream, coh, entt, out);
}

// Round 2
// 116.549 us; speedup vs baseline: 1.4561x; 1.4561x over previous
//
#include <hip/hip_runtime.h>
#include <math.h>

#define PI_F 3.14159265358979323846f

typedef __attribute__((ext_vector_type(8))) short short8v;
typedef __attribute__((ext_vector_type(4))) float f32x4;

__device__ __forceinline__ unsigned short f2bf(float f) {
    unsigned int u = __float_as_uint(f);
    u += 0x7fffu + ((u >> 16) & 1u);
    return (unsigned short)(u >> 16);
}

__device__ __forceinline__ void gload_lds16(const void* g, void* l) {
    __builtin_amdgcn_global_load_lds((const __attribute__((address_space(1))) unsigned int*)g,
                                     (__attribute__((address_space(3))) unsigned int*)l, 16, 0, 0);
}

// ---------------- prep: f32 -> bf16 converts + W transposes ----------------
// z=0: audio convert, z=1: visual convert, z=2..5: transpose-convert Wq,Wk,Wv,Wo
__global__ __launch_bounds__(256) void prep_bf16(const float* __restrict__ audio,
                                                 const float* __restrict__ visual,
                                                 const float* __restrict__ Wq,
                                                 const float* __restrict__ Wk,
                                                 const float* __restrict__ Wv,
                                                 const float* __restrict__ Wo,
                                                 unsigned short* __restrict__ audio_b,
                                                 unsigned short* __restrict__ visual_b,
                                                 unsigned short* __restrict__ Wqt,
                                                 unsigned short* __restrict__ Wkt,
                                                 unsigned short* __restrict__ Wvt,
                                                 unsigned short* __restrict__ Wot) {
    const int z = blockIdx.z;
    const int tx = threadIdx.x & 31, ty = threadIdx.x >> 5;  // 32x8
    const int x0 = blockIdx.x * 32, y0 = blockIdx.y * 32;
    if (z < 2) {
        const float* src = z ? visual : audio;
        unsigned short* dst = z ? visual_b : audio_b;
#pragma unroll
        for (int i = 0; i < 4; i++) {
            int r = y0 + ty + i * 8;
            dst[r * 512 + x0 + tx] = f2bf(src[r * 512 + x0 + tx]);
        }
    } else {
        const float* src = (z == 2) ? Wq : (z == 3) ? Wk : (z == 4) ? Wv : Wo;
        unsigned short* dst = (z == 2) ? Wqt : (z == 3) ? Wkt : (z == 4) ? Wvt : Wot;
        __shared__ float tile[32][33];
#pragma unroll
        for (int i = 0; i < 4; i++)
            tile[ty + i * 8][tx] = src[(y0 + ty + i * 8) * 512 + x0 + tx];
        __syncthreads();
        // dst[n][k] = W[k][n]
#pragma unroll
        for (int i = 0; i < 4; i++) {
            int n = x0 + ty + i * 8;
            dst[n * 512 + y0 + tx] = f2bf(tile[tx][ty + i * 8]);
        }
    }
}

// ---------------- bf16 MFMA GEMM: C = A @ Bt^T + bias ----------------
// A [M][512] bf16 row-major; Bt [512(N rows)][512(K)] bf16; C f32 [M][512].
// 64x64 tile, BK=64, 4 waves (2x2), each wave 32x32 (2x2 16x16 frags).
struct MfmaArgs {
    const unsigned short* A[4];
    const unsigned short* Bt[4];
    const float* bias[4];
    float* C[4];
};

__global__ __launch_bounds__(256) void gemm_mfma(MfmaArgs args) {
    const int zb = blockIdx.z;
    const unsigned short* __restrict__ A = args.A[zb];
    const unsigned short* __restrict__ Bt = args.Bt[zb];
    const float* __restrict__ bias = args.bias[zb];
    float* __restrict__ C = args.C[zb];

    const int n0 = blockIdx.x * 64;
    const int m0 = blockIdx.y * 64;

    __shared__ unsigned short As[64 * 64];
    __shared__ unsigned short Bs[64 * 64];

    const int tid = threadIdx.x;
    const int lane = tid & 63;
    const int wid = tid >> 6;
    const int wr = wid >> 1, wc = wid & 1;
    const int l15 = lane & 15;
    const int lhi = lane >> 4;

    f32x4 acc[2][2] = {};

    for (int kt = 0; kt < 8; kt++) {
        const int k0 = kt * 64;
        // stage: linear LDS dest (wave base + lane*16), inverse-swizzled global src.
        // physical layout: row r (128B) holds logical 16B-chunk lc at slot lc^(r&7).
#pragma unroll
        for (int i = 0; i < 2; i++) {
            int row = i * 32 + wid * 8 + (lane >> 3);
            int pc = lane & 7;
            int lc = pc ^ (row & 7);
            const unsigned short* gA = A + (m0 + row) * 512 + k0 + lc * 8;
            const unsigned short* gB = Bt + (n0 + row) * 512 + k0 + lc * 8;
            gload_lds16(gA, (char*)As + i * 4096 + wid * 1024);
            gload_lds16(gB, (char*)Bs + i * 4096 + wid * 1024);
        }
        __syncthreads();
#pragma unroll
        for (int ks = 0; ks < 2; ks++) {
            short8v a[2], b[2];
            const int lcr = ks * 4 + lhi;
#pragma unroll
            for (int qi = 0; qi < 2; qi++) {
                int row = wr * 32 + qi * 16 + l15;
                int pcc = lcr ^ (row & 7);
                a[qi] = *(const short8v*)((const char*)As + row * 128 + pcc * 16);
            }
#pragma unroll
            for (int nj = 0; nj < 2; nj++) {
                int row = wc * 32 + nj * 16 + l15;
                int pcc = lcr ^ (row & 7);
                b[nj] = *(const short8v*)((const char*)Bs + row * 128 + pcc * 16);
            }
#pragma unroll
            for (int qi = 0; qi < 2; qi++)
#pragma unroll
                for (int nj = 0; nj < 2; nj++)
                    acc[qi][nj] = __builtin_amdgcn_mfma_f32_16x16x32_bf16(a[qi], b[nj], acc[qi][nj], 0, 0, 0);
        }
        __syncthreads();
    }

    // epilogue: C/D layout col=lane&15, row=(lane>>4)*4+reg
#pragma unroll
    for (int qi = 0; qi < 2; qi++)
#pragma unroll
        for (int nj = 0; nj < 2; nj++)
#pragma unroll
            for (int r = 0; r < 4; r++) {
                int row = m0 + wr * 32 + qi * 16 + lhi * 4 + r;
                int col = n0 + wc * 32 + nj * 16 + l15;
                C[row * 512 + col] = acc[qi][nj][r] + bias[col];
            }
}

// ---------------- per-token quantum scalar path ----------------
__global__ __launch_bounds__(64) void token_scalars(const float* __restrict__ xa,
                                                    const float* __restrict__ xv,
                                                    const float* __restrict__ We,
                                                    const float* __restrict__ be,
                                                    float* __restrict__ scale,
                                                    float* __restrict__ coh_tok,
                                                    float* __restrict__ ent_tok) {
    const int t = blockIdx.x;
    const int lane = threadIdx.x;

    __shared__ __align__(16) float xs[2][512];
    const float4* xaRow = (const float4*)(xa + t * 512);
    const float4* xvRow = (const float4*)(xv + t * 512);
#pragma unroll
    for (int i = lane; i < 128; i += 64) {
        ((float4*)xs[0])[i] = xaRow[i];
        ((float4*)xs[1])[i] = xvRow[i];
    }
    __syncthreads();

    float accA[8] = {}, accV[8] = {};
#pragma unroll
    for (int i = 0; i < 8; i++) {
        int k = i * 64 + lane;
        float wa = xs[0][k], wv = xs[1][k];
        const float* wrow = &We[k * 512];
#pragma unroll
        for (int c = 0; c < 8; c++) {
            float w = wrow[c];
            accA[c] += wa * w;
            accV[c] += wv * w;
        }
    }
#pragma unroll
    for (int c = 0; c < 8; c++) {
#pragma unroll
        for (int o = 32; o >= 1; o >>= 1) {
            accA[c] += __shfl_xor(accA[c], o);
            accV[c] += __shfl_xor(accV[c], o);
        }
    }
    if (lane == 0) {
        float pa = 1.f, pv = 1.f;
#pragma unroll
        for (int c = 0; c < 8; c++) {
            pa *= cosf((accA[c] + be[c]) * (PI_F * 0.5f));
            pv *= cosf((accV[c] + be[c]) * (PI_F * 0.5f));
        }
        float s0a = pa / (fabsf(pa) + 1e-10f);
        float s0v = pv / (fabsf(pv) + 1e-10f);
        float e = s0a * s0v;
        const float a = 0.7071f;
        float ent0 = a * e;
        float qsum = 2.f * ent0 * ent0;
        float interf = (ent0 < 0.f) ? cosf(2.f * PI_F / 65536.f) : 1.f;
        scale[t] = qsum * interf;
        coh_tok[t] = 2.f * fabsf(ent0);
        float p = (ent0 * ent0) / (qsum + 1e-10f);
        ent_tok[t] = -2.f * p * logf(p + 1e-10f);
    }
}

// ---------------- attention: logits + softmax, one block per (b,h,q) ----------------
__global__ __launch_bounds__(256) void attn_softmax(const float* __restrict__ aq,
                                                    const float* __restrict__ vk,
                                                    const float* __restrict__ scale,
                                                    float* __restrict__ attn,
                                                    float* __restrict__ attn_last) {
    const int q = blockIdx.x, h = blockIdx.y, b = blockIdx.z;
    const int k = threadIdx.x;

    __shared__ __align__(16) float qrow[64];
    __shared__ float redm[4], reds[4];

    if (k < 64) qrow[k] = aq[(b * 256 + q) * 512 + h * 64 + k];
    __syncthreads();

    const float* vrow = &vk[(b * 256 + k) * 512 + h * 64];
    float dot = 0.f;
#pragma unroll
    for (int j = 0; j < 64; j += 4) {
        float4 v = *(const float4*)(vrow + j);
        float4 qv = *(const float4*)(qrow + j);
        dot += v.x * qv.x + v.y * qv.y + v.z * qv.z + v.w * qv.w;
    }
    float logit = dot * scale[b * 256 + q] * 0.125f;

    const int wid = k >> 6, lane = k & 63;
    float m = logit;
#pragma unroll
    for (int o = 32; o >= 1; o >>= 1) m = fmaxf(m, __shfl_xor(m, o));
    if (lane == 0) redm[wid] = m;
    __syncthreads();
    m = fmaxf(fmaxf(redm[0], redm[1]), fmaxf(redm[2], redm[3]));

    float ex = expf(logit - m);
    float s = ex;
#pragma unroll
    for (int o = 32; o >= 1; o >>= 1) s += __shfl_xor(s, o);
    if (lane == 0) reds[wid] = s;
    __syncthreads();
    s = reds[0] + reds[1] + reds[2] + reds[3];

    float p = ex / s;
    attn[((b * 8 + h) * 256 + q) * 256 + k] = p;
    if (h == 7) attn_last[(b * 256 + q) * 256 + k] = p;
}

// ---------------- audio_att (bf16 out) ----------------
__global__ __launch_bounds__(64) void av_audio(const float* __restrict__ attn,
                                               const float* __restrict__ vv,
                                               unsigned short* __restrict__ out) {
    const int q = blockIdx.x, h = blockIdx.y, b = blockIdx.z, d = threadIdx.x;
    __shared__ __align__(16) float arow[256];
    const float4* ap = (const float4*)&attn[((b * 8 + h) * 256 + q) * 256];
    ((float4*)arow)[d] = ap[d];
    __syncthreads();
    float acc = 0.f;
    const float* vbase = &vv[b * 256 * 512 + h * 64 + d];
#pragma unroll 4
    for (int k = 0; k < 256; k++) acc += arow[k] * vbase[k * 512];
    out[(b * 256 + q) * 512 + h * 64 + d] = f2bf(acc);
}

// ---------------- visual_att (bf16 out) ----------------
__global__ __launch_bounds__(64) void av_visual(const float* __restrict__ attn,
                                                const float* __restrict__ av,
                                                unsigned short* __restrict__ out) {
    const int kk = blockIdx.x, h = blockIdx.y, b = blockIdx.z, d = threadIdx.x;
    __shared__ float acol[256];
    for (int i = d; i < 256; i += 64) acol[i] = attn[((b * 8 + h) * 256 + i) * 256 + kk];
    __syncthreads();
    float acc = 0.f;
    const float* abase = &av[b * 256 * 512 + h * 64 + d];
#pragma unroll 4
    for (int q = 0; q < 256; q++) acc += acol[q] * abase[q * 512];
    out[(b * 256 + kk) * 512 + h * 64 + d] = f2bf(acc);
}

// ---------------- residual + LayerNorm ----------------
__global__ __launch_bounds__(256) void ln_kernel(const float* __restrict__ xa,
                                                 const float* __restrict__ xv,
                                                 const float* __restrict__ proj,
                                                 const float* __restrict__ gamma,
                                                 const float* __restrict__ beta,
                                                 float* __restrict__ out) {
    const int t = blockIdx.x;
    const int tid = threadIdx.x;
    const float* x = (t < 512) ? (xa + t * 512) : (xv + (t - 512) * 512);
    const float* p = proj + t * 512;

    float y0 = x[tid] + p[tid];
    float y1 = x[tid + 256] + p[tid + 256];

    __shared__ float red[4];
    const int wid = tid >> 6, lane = tid & 63;

    float s = y0 + y1;
#pragma unroll
    for (int o = 32; o >= 1; o >>= 1) s += __shfl_xor(s, o);
    if (lane == 0) red[wid] = s;
    __syncthreads();
    float mean = (red[0] + red[1] + red[2] + red[3]) * (1.f / 512.f);

    float d0 = y0 - mean, d1 = y1 - mean;
    float v = d0 * d0 + d1 * d1;
    __syncthreads();
#pragma unroll
    for (int o = 32; o >= 1; o >>= 1) v += __shfl_xor(v, o);
    if (lane == 0) red[wid] = v;
    __syncthreads();
    float var = (red[0] + red[1] + red[2] + red[3]) * (1.f / 512.f);
    float rstd = rsqrtf(var + 1e-5f);

    out[t * 512 + tid] = d0 * rstd * gamma[tid] + beta[tid];
    out[t * 512 + tid + 256] = d1 * rstd * gamma[tid + 256] + beta[tid + 256];
}

// ---------------- final scalar reduction ----------------
__global__ __launch_bounds__(512) void finalize_scalars(const float* __restrict__ coh,
                                                        const float* __restrict__ entt,
                                                        float* __restrict__ out) {
    const int tid = threadIdx.x;
    float c = coh[tid], e = entt[tid];
    const int wid = tid >> 6, lane = tid & 63;
    __shared__ float rc[8], re[8];
#pragma unroll
    for (int o = 32; o >= 1; o >>= 1) {
        c += __shfl_xor(c, o);
        e += __shfl_xor(e, o);
    }
    if (lane == 0) { rc[wid] = c; re[wid] = e; }
    __syncthreads();
    if (tid == 0) {
        float cs = 0.f, es = 0.f;
#pragma unroll
        for (int i = 0; i < 8; i++) { cs += rc[i]; es += re[i]; }
        out[524288] = cs / (512.f * 65536.f);
        out[524289] = es / 512.f;
    }
}

extern "C" void kernel_launch(void* const* d_in, const int* in_sizes, int n_in,
                              void* d_out, int out_size, void* d_ws, size_t ws_size,
                              hipStream_t stream) {
    const float* audio  = (const float*)d_in[0];
    const float* visual = (const float*)d_in[1];
    const float* Wq = (const float*)d_in[2];
    const float* bq = (const float*)d_in[3];
    const float* Wk = (const float*)d_in[4];
    const float* bk = (const float*)d_in[5];
    const float* Wv = (const float*)d_in[6];
    const float* bv = (const float*)d_in[7];
    const float* Wo = (const float*)d_in[8];
    const float* bo = (const float*)d_in[9];
    const float* We = (const float*)d_in[10];
    const float* be = (const float*)d_in[11];
    const float* gamma = (const float*)d_in[12];
    const float* beta  = (const float*)d_in[13];
    float* out = (float*)d_out;

    float* ws = (float*)d_ws;
    float* aq    = ws;                   // 262144 f32
    float* vk    = ws + 262144;          // 262144
    float* vv    = ws + 524288;          // 262144
    float* av    = ws + 786432;          // 262144
    float* proj  = ws + 1048576;         // 524288
    float* attn  = ws + 1572864;         // 1048576
    float* scale = ws + 2621440;         // 512
    float* coh   = ws + 2621952;         // 512
    float* entt  = ws + 2622464;         // 512
    unsigned short* attcat_b = (unsigned short*)(ws + 2623488);  // 524288 bf16
    unsigned short* audio_b  = (unsigned short*)(ws + 2885632);  // 262144 bf16
    unsigned short* visual_b = (unsigned short*)(ws + 3016704);
    unsigned short* Wqt = (unsigned short*)(ws + 3147776);
    unsigned short* Wkt = (unsigned short*)(ws + 3278848);
    unsigned short* Wvt = (unsigned short*)(ws + 3409920);
    unsigned short* Wot = (unsigned short*)(ws + 3540992);

    // 0) bf16 conversion + weight transposes
    hipLaunchKernelGGL(prep_bf16, dim3(16, 16, 6), dim3(256), 0, stream,
                       audio, visual, Wq, Wk, Wv, Wo,
                       audio_b, visual_b, Wqt, Wkt, Wvt, Wot);

    // 1) projections (MFMA): aq=Xa@Wq, vk=Xv@Wk, vv=Xv@Wv, av=Xa@Wv
    MfmaArgs g1;
    g1.A[0] = audio_b;  g1.Bt[0] = Wqt; g1.bias[0] = bq; g1.C[0] = aq;
    g1.A[1] = visual_b; g1.Bt[1] = Wkt; g1.bias[1] = bk; g1.C[1] = vk;
    g1.A[2] = visual_b; g1.Bt[2] = Wvt; g1.bias[2] = bv; g1.C[2] = vv;
    g1.A[3] = audio_b;  g1.Bt[3] = Wvt; g1.bias[3] = bv; g1.C[3] = av;
    hipLaunchKernelGGL(gemm_mfma, dim3(8, 8, 4), dim3(256), 0, stream, g1);

    // 2) per-token scalar path
    hipLaunchKernelGGL(token_scalars, dim3(512), dim3(64), 0, stream,
                       audio, visual, We, be, scale, coh, entt);

    // 3) attention logits + softmax (+ attn[:,7] output)
    hipLaunchKernelGGL(attn_softmax, dim3(256, 8, 2), dim3(256), 0, stream,
                       aq, vk, scale, attn, out + 524290);

    // 4) audio_att = attn @ vv_heads (bf16 out)
    hipLaunchKernelGGL(av_audio, dim3(256, 8, 2), dim3(64), 0, stream, attn, vv, attcat_b);

    // 5) visual_att = attn^T @ av_heads (bf16 out)
    hipLaunchKernelGGL(av_visual, dim3(256, 8, 2), dim3(64), 0, stream, attn, av, attcat_b + 262144);

    // 6) output projection (MFMA): proj = attcat @ Wo + bo   (M=1024)
    MfmaArgs g2;
    for (int i = 0; i < 4; i++) { g2.A[i] = attcat_b; g2.Bt[i] = Wot; g2.bias[i] = bo; g2.C[i] = proj; }
    hipLaunchKernelGGL(gemm_mfma, dim3(8, 16, 1), dim3(256), 0, stream, g2);

    // 7) residual + LN
    hipLaunchKernelGGL(ln_kernel, dim3(1024), dim3(256), 0, stream,
                       audio, visual, proj, gamma, beta, out);

    // 8) scalars
    hipLaunchKernelGGL(finalize_scalars, dim3(1), dim3(512), 0, stream, coh, entt, out);
}

// Round 4
// 71.583 us; speedup vs baseline: 2.3708x; 1.6282x over previous
//
#include <hip/hip_runtime.h>
#include <math.h>

#define PI_F 3.14159265358979323846f

typedef __attribute__((ext_vector_type(8))) short short8v;
typedef __attribute__((ext_vector_type(4))) float f32x4;
typedef __attribute__((ext_vector_type(16))) float f32x16;

__device__ __forceinline__ unsigned short f2bf(float f) {
    unsigned int u = __float_as_uint(f);
    u += 0x7fffu + ((u >> 16) & 1u);
    return (unsigned short)(u >> 16);
}

__device__ __forceinline__ unsigned int cvtpk_bf16(float lo, float hi) {
    unsigned int r;
    asm("v_cvt_pk_bf16_f32 %0, %1, %2" : "=v"(r) : "v"(lo), "v"(hi));
    return r;
}

union W8 { unsigned int w[4]; short8v v; };

__device__ __forceinline__ void gload_lds16(const void* g, void* l) {
    __builtin_amdgcn_global_load_lds((const __attribute__((address_space(1))) unsigned int*)g,
                                     (__attribute__((address_space(3))) unsigned int*)l, 16, 0, 0);
}

// ---------------- prep: f32 -> bf16 converts + W transposes ----------------
__global__ __launch_bounds__(256) void prep_bf16(const float* __restrict__ audio,
                                                 const float* __restrict__ visual,
                                                 const float* __restrict__ Wq,
                                                 const float* __restrict__ Wk,
                                                 const float* __restrict__ Wv,
                                                 const float* __restrict__ Wo,
                                                 unsigned short* __restrict__ audio_b,
                                                 unsigned short* __restrict__ visual_b,
                                                 unsigned short* __restrict__ Wqt,
                                                 unsigned short* __restrict__ Wkt,
                                                 unsigned short* __restrict__ Wvt,
                                                 unsigned short* __restrict__ Wot) {
    const int z = blockIdx.z;
    const int tx = threadIdx.x & 31, ty = threadIdx.x >> 5;
    const int x0 = blockIdx.x * 32, y0 = blockIdx.y * 32;
    if (z < 2) {
        const float* src = z ? visual : audio;
        unsigned short* dst = z ? visual_b : audio_b;
#pragma unroll
        for (int i = 0; i < 4; i++) {
            int r = y0 + ty + i * 8;
            dst[r * 512 + x0 + tx] = f2bf(src[r * 512 + x0 + tx]);
        }
    } else {
        const float* src = (z == 2) ? Wq : (z == 3) ? Wk : (z == 4) ? Wv : Wo;
        unsigned short* dst = (z == 2) ? Wqt : (z == 3) ? Wkt : (z == 4) ? Wvt : Wot;
        __shared__ float tile[32][33];
#pragma unroll
        for (int i = 0; i < 4; i++)
            tile[ty + i * 8][tx] = src[(y0 + ty + i * 8) * 512 + x0 + tx];
        __syncthreads();
#pragma unroll
        for (int i = 0; i < 4; i++) {
            int n = x0 + ty + i * 8;
            dst[n * 512 + y0 + tx] = f2bf(tile[tx][ty + i * 8]);
        }
    }
}

// ---------------- bf16 MFMA GEMM: C = A @ Bt^T + bias (validated r2) ----------------
struct MfmaArgs {
    const unsigned short* A[4];
    const unsigned short* Bt[4];
    const float* bias[4];
    float* C[4];
};

__global__ __launch_bounds__(256) void gemm_mfma(MfmaArgs args) {
    const int zb = blockIdx.z;
    const unsigned short* __restrict__ A = args.A[zb];
    const unsigned short* __restrict__ Bt = args.Bt[zb];
    const float* __restrict__ bias = args.bias[zb];
    float* __restrict__ C = args.C[zb];

    const int n0 = blockIdx.x * 64;
    const int m0 = blockIdx.y * 64;

    __shared__ unsigned short As[64 * 64];
    __shared__ unsigned short Bs[64 * 64];

    const int tid = threadIdx.x;
    const int lane = tid & 63;
    const int wid = tid >> 6;
    const int wr = wid >> 1, wc = wid & 1;
    const int l15 = lane & 15;
    const int lhi = lane >> 4;

    f32x4 acc[2][2] = {};

    for (int kt = 0; kt < 8; kt++) {
        const int k0 = kt * 64;
#pragma unroll
        for (int i = 0; i < 2; i++) {
            int row = i * 32 + wid * 8 + (lane >> 3);
            int pc = lane & 7;
            int lc = pc ^ (row & 7);
            const unsigned short* gA = A + (m0 + row) * 512 + k0 + lc * 8;
            const unsigned short* gB = Bt + (n0 + row) * 512 + k0 + lc * 8;
            gload_lds16(gA, (char*)As + i * 4096 + wid * 1024);
            gload_lds16(gB, (char*)Bs + i * 4096 + wid * 1024);
        }
        __syncthreads();
#pragma unroll
        for (int ks = 0; ks < 2; ks++) {
            short8v a[2], b[2];
            const int lcr = ks * 4 + lhi;
#pragma unroll
            for (int qi = 0; qi < 2; qi++) {
                int row = wr * 32 + qi * 16 + l15;
                int pcc = lcr ^ (row & 7);
                a[qi] = *(const short8v*)((const char*)As + row * 128 + pcc * 16);
            }
#pragma unroll
            for (int nj = 0; nj < 2; nj++) {
                int row = wc * 32 + nj * 16 + l15;
                int pcc = lcr ^ (row & 7);
                b[nj] = *(const short8v*)((const char*)Bs + row * 128 + pcc * 16);
            }
#pragma unroll
            for (int qi = 0; qi < 2; qi++)
#pragma unroll
                for (int nj = 0; nj < 2; nj++)
                    acc[qi][nj] = __builtin_amdgcn_mfma_f32_16x16x32_bf16(a[qi], b[nj], acc[qi][nj], 0, 0, 0);
        }
        __syncthreads();
    }

#pragma unroll
    for (int qi = 0; qi < 2; qi++)
#pragma unroll
        for (int nj = 0; nj < 2; nj++)
#pragma unroll
            for (int r = 0; r < 4; r++) {
                int row = m0 + wr * 32 + qi * 16 + lhi * 4 + r;
                int col = n0 + wc * 32 + nj * 16 + l15;
                C[row * 512 + col] = acc[qi][nj][r] + bias[col];
            }
}

// ---------------- per-token quantum scalar path ----------------
__global__ __launch_bounds__(64) void token_scalars(const float* __restrict__ xa,
                                                    const float* __restrict__ xv,
                                                    const float* __restrict__ We,
                                                    const float* __restrict__ be,
                                                    float* __restrict__ scale,
                                                    float* __restrict__ coh_tok,
                                                    float* __restrict__ ent_tok) {
    const int t = blockIdx.x;
    const int lane = threadIdx.x;

    __shared__ __align__(16) float xs[2][512];
    const float4* xaRow = (const float4*)(xa + t * 512);
    const float4* xvRow = (const float4*)(xv + t * 512);
#pragma unroll
    for (int i = lane; i < 128; i += 64) {
        ((float4*)xs[0])[i] = xaRow[i];
        ((float4*)xs[1])[i] = xvRow[i];
    }
    __syncthreads();

    float accA[8] = {}, accV[8] = {};
#pragma unroll
    for (int i = 0; i < 8; i++) {
        int k = i * 64 + lane;
        float wa = xs[0][k], wv = xs[1][k];
        const float* wrow = &We[k * 512];
#pragma unroll
        for (int c = 0; c < 8; c++) {
            float w = wrow[c];
            accA[c] += wa * w;
            accV[c] += wv * w;
        }
    }
#pragma unroll
    for (int c = 0; c < 8; c++) {
#pragma unroll
        for (int o = 32; o >= 1; o >>= 1) {
            accA[c] += __shfl_xor(accA[c], o);
            accV[c] += __shfl_xor(accV[c], o);
        }
    }
    if (lane == 0) {
        float pa = 1.f, pv = 1.f;
#pragma unroll
        for (int c = 0; c < 8; c++) {
            pa *= cosf((accA[c] + be[c]) * (PI_F * 0.5f));
            pv *= cosf((accV[c] + be[c]) * (PI_F * 0.5f));
        }
        float s0a = pa / (fabsf(pa) + 1e-10f);
        float s0v = pv / (fabsf(pv) + 1e-10f);
        float e = s0a * s0v;
        const float a = 0.7071f;
        float ent0 = a * e;
        float qsum = 2.f * ent0 * ent0;
        float interf = (ent0 < 0.f) ? cosf(2.f * PI_F / 65536.f) : 1.f;
        scale[t] = qsum * interf;
        coh_tok[t] = 2.f * fabsf(ent0);
        float p = (ent0 * ent0) / (qsum + 1e-10f);
        ent_tok[t] = -2.f * p * logf(p + 1e-10f);
    }
}

// ---------------- fused attention: QK^T + softmax + PV + P^T AV ----------------
// One block per (b,h), 512 threads = 8 waves. LDS = 64KB (Q,K staging only).
// P^T round-trips through global scratch p_t (L2-resident); intra-block RAW is
// made visible by __threadfence_block + __syncthreads (same CU/L1/L2).
__global__ __launch_bounds__(512, 2) void fused_attn(const float* __restrict__ aq,
                                                     const float* __restrict__ vk,
                                                     const float* __restrict__ vv,
                                                     const float* __restrict__ av,
                                                     const float* __restrict__ scale,
                                                     unsigned short* __restrict__ p_t,
                                                     unsigned short* __restrict__ attcat_b,
                                                     float* __restrict__ attn_last) {
    extern __shared__ char smem[];
    char* Qb = smem;            // [256][64] bf16, 128B rows, chunk-swizzled
    char* Kb = smem + 32768;

    const int h = blockIdx.x, b = blockIdx.y;
    const int tid = threadIdx.x;
    const int wid = tid >> 6;
    const int lane = tid & 63;
    const int lq = lane & 31;
    const int hi = lane >> 5;

    // ---- stage Q, K (f32 global -> bf16 LDS, swizzled) ----
    {
        int r = tid >> 1, ch = tid & 1;
        const float* qsrc = aq + (size_t)(b * 256 + r) * 512 + h * 64 + ch * 32;
        const float* ksrc = vk + (size_t)(b * 256 + r) * 512 + h * 64 + ch * 32;
#pragma unroll
        for (int i = 0; i < 4; i++) {
            float4 a0 = *(const float4*)(qsrc + i * 8);
            float4 a1 = *(const float4*)(qsrc + i * 8 + 4);
            W8 u;
            u.w[0] = cvtpk_bf16(a0.x, a0.y); u.w[1] = cvtpk_bf16(a0.z, a0.w);
            u.w[2] = cvtpk_bf16(a1.x, a1.y); u.w[3] = cvtpk_bf16(a1.z, a1.w);
            int slot = (ch * 4 + i) ^ (r & 7);
            *(short8v*)(Qb + r * 128 + (slot << 4)) = u.v;
            float4 b0 = *(const float4*)(ksrc + i * 8);
            float4 b1 = *(const float4*)(ksrc + i * 8 + 4);
            W8 vw;
            vw.w[0] = cvtpk_bf16(b0.x, b0.y); vw.w[1] = cvtpk_bf16(b0.z, b0.w);
            vw.w[2] = cvtpk_bf16(b1.x, b1.y); vw.w[3] = cvtpk_bf16(b1.z, b1.w);
            *(short8v*)(Kb + r * 128 + (slot << 4)) = vw.v;
        }
    }
    __syncthreads();

    // ---- QK^T (swapped, 32x32x16): p[t][r] = S[q=wid*32+lq][k=32t+crow(r,hi)] ----
    f32x16 p[8] = {};
    {
        short8v qf[4];
        const int qrow = wid * 32 + lq;
#pragma unroll
        for (int s = 0; s < 4; s++) {
            int slot = (2 * s + hi) ^ (qrow & 7);
            qf[s] = *(const short8v*)(Qb + qrow * 128 + (slot << 4));
        }
#pragma unroll
        for (int t = 0; t < 8; t++) {
            const int krow = t * 32 + lq;
#pragma unroll
            for (int s = 0; s < 4; s++) {
                int slot = (2 * s + hi) ^ (krow & 7);
                short8v kf = *(const short8v*)(Kb + krow * 128 + (slot << 4));
                p[t] = __builtin_amdgcn_mfma_f32_32x32x16_bf16(kf, qf[s], p[t], 0, 0, 0);
            }
        }
    }

    // ---- softmax over k (lane-local + one xor32) ----
    {
        const float sq = scale[b * 256 + wid * 32 + lq] * 0.125f;
        float mx = -1e30f;
#pragma unroll
        for (int t = 0; t < 8; t++) {
            p[t] *= sq;
#pragma unroll
            for (int r = 0; r < 16; r++) mx = fmaxf(mx, p[t][r]);
        }
        mx = fmaxf(mx, __shfl_xor(mx, 32));
        float sum = 0.f;
#pragma unroll
        for (int t = 0; t < 8; t++)
#pragma unroll
            for (int r = 0; r < 16; r++) {
                float e = __expf(p[t][r] - mx);
                p[t][r] = e;
                sum += e;
            }
        sum += __shfl_xor(sum, 32);
        float inv = 1.0f / sum;
#pragma unroll
        for (int t = 0; t < 8; t++) p[t] *= inv;
    }

    // ---- audio PV: A-frags built via cvt_pk + shfl_xor(32) partner exchange ----
    f32x16 aacc[2] = {};
#pragma unroll
    for (int t = 0; t < 8; t++) {
        // packed pairs; k-offsets (from 32t): hi=0: c0={0,1} c1={2,3} c2={8,9} c3={10,11}
        //                                     hi=1: c0={4,5} c1={6,7} c2={12,13} c3={14,15}
        unsigned int c0 = cvtpk_bf16(p[t][0], p[t][1]);
        unsigned int c1 = cvtpk_bf16(p[t][2], p[t][3]);
        unsigned int c2 = cvtpk_bf16(p[t][4], p[t][5]);
        unsigned int c3 = cvtpk_bf16(p[t][6], p[t][7]);
        unsigned int e0 = (unsigned int)__shfl_xor((int)c0, 32);
        unsigned int e1 = (unsigned int)__shfl_xor((int)c1, 32);
        unsigned int e2 = (unsigned int)__shfl_xor((int)c2, 32);
        unsigned int e3 = (unsigned int)__shfl_xor((int)c3, 32);
        W8 fa0;  // k = 32t + 8*hi + 0..7
        fa0.w[0] = hi ? e2 : c0;
        fa0.w[1] = hi ? e3 : c1;
        fa0.w[2] = hi ? c2 : e0;
        fa0.w[3] = hi ? c3 : e1;
        unsigned int c4 = cvtpk_bf16(p[t][8], p[t][9]);
        unsigned int c5 = cvtpk_bf16(p[t][10], p[t][11]);
        unsigned int c6 = cvtpk_bf16(p[t][12], p[t][13]);
        unsigned int c7 = cvtpk_bf16(p[t][14], p[t][15]);
        unsigned int e4 = (unsigned int)__shfl_xor((int)c4, 32);
        unsigned int e5 = (unsigned int)__shfl_xor((int)c5, 32);
        unsigned int e6 = (unsigned int)__shfl_xor((int)c6, 32);
        unsigned int e7 = (unsigned int)__shfl_xor((int)c7, 32);
        W8 fa1;  // k = 32t + 16 + 8*hi + 0..7
        fa1.w[0] = hi ? e6 : c4;
        fa1.w[1] = hi ? e7 : c5;
        fa1.w[2] = hi ? c6 : e4;
        fa1.w[3] = hi ? c7 : e5;
#pragma unroll
        for (int dt = 0; dt < 2; dt++) {
            const float* vb0 = vv + (size_t)(b * 256 + 32 * t + 8 * hi) * 512 + h * 64 + 32 * dt + lq;
            W8 vf;
            vf.w[0] = cvtpk_bf16(vb0[0 * 512], vb0[1 * 512]);
            vf.w[1] = cvtpk_bf16(vb0[2 * 512], vb0[3 * 512]);
            vf.w[2] = cvtpk_bf16(vb0[4 * 512], vb0[5 * 512]);
            vf.w[3] = cvtpk_bf16(vb0[6 * 512], vb0[7 * 512]);
            aacc[dt] = __builtin_amdgcn_mfma_f32_32x32x16_bf16(fa0.v, vf.v, aacc[dt], 0, 0, 0);
            const float* vb1 = vb0 + 16 * 512;
            W8 vg;
            vg.w[0] = cvtpk_bf16(vb1[0 * 512], vb1[1 * 512]);
            vg.w[1] = cvtpk_bf16(vb1[2 * 512], vb1[3 * 512]);
            vg.w[2] = cvtpk_bf16(vb1[4 * 512], vb1[5 * 512]);
            vg.w[3] = cvtpk_bf16(vb1[6 * 512], vb1[7 * 512]);
            aacc[dt] = __builtin_amdgcn_mfma_f32_32x32x16_bf16(fa1.v, vg.v, aacc[dt], 0, 0, 0);
        }
    }
#pragma unroll
    for (int dt = 0; dt < 2; dt++)
#pragma unroll
        for (int r = 0; r < 16; r++) {
            int qrow = wid * 32 + (r & 3) + 8 * (r >> 2) + 4 * hi;
            attcat_b[(size_t)(b * 256 + qrow) * 512 + h * 64 + 32 * dt + lq] = f2bf(aacc[dt][r]);
        }

    // ---- write P^T (bf16) to global scratch: p_t[(b*8+h)][k][q] ----
    {
        unsigned short* pdst = p_t + (size_t)(b * 8 + h) * 65536;
#pragma unroll
        for (int t = 0; t < 8; t++)
#pragma unroll
            for (int r = 0; r < 16; r++) {
                int k = 32 * t + (r & 3) + 8 * (r >> 2) + 4 * hi;
                pdst[k * 256 + wid * 32 + lq] = f2bf(p[t][r]);
            }
    }
    __threadfence_block();
    __syncthreads();  // Q/K reads done; P^T writes drained to L2

    // ---- attn[:, 7] output (f32), per-wave LDS transpose tile ----
    if (h == 7) {
        float* tile = (float*)smem + (size_t)wid * (32 * 33);
        const int q2 = lane >> 1, koff = (lane & 1) * 16;
#pragma unroll
        for (int t = 0; t < 8; t++) {
#pragma unroll
            for (int r = 0; r < 16; r++)
                tile[lq * 33 + ((r & 3) + 8 * (r >> 2) + 4 * hi)] = p[t][r];
            __syncthreads();
            float* orow = attn_last + (size_t)(b * 256 + wid * 32 + q2) * 256 + 32 * t + koff;
#pragma unroll
            for (int j = 0; j < 16; j++) orow[j] = tile[q2 * 33 + koff + j];
            __syncthreads();
        }
    }

    // ---- visual: out[k][d] = sum_q P^T[k][q] AV[q][d] ----
    f32x16 vacc[2] = {};
    {
        const int krow = wid * 32 + lq;
        const unsigned short* prow = p_t + (size_t)(b * 8 + h) * 65536 + (size_t)krow * 256;
#pragma unroll
        for (int u = 0; u < 16; u++) {
            short8v pa = *(const short8v*)(prow + 16 * u + 8 * hi);
#pragma unroll
            for (int dt = 0; dt < 2; dt++) {
                const float* ab = av + (size_t)(b * 256 + 16 * u + 8 * hi) * 512 + h * 64 + 32 * dt + lq;
                W8 af;
                af.w[0] = cvtpk_bf16(ab[0 * 512], ab[1 * 512]);
                af.w[1] = cvtpk_bf16(ab[2 * 512], ab[3 * 512]);
                af.w[2] = cvtpk_bf16(ab[4 * 512], ab[5 * 512]);
                af.w[3] = cvtpk_bf16(ab[6 * 512], ab[7 * 512]);
                vacc[dt] = __builtin_amdgcn_mfma_f32_32x32x16_bf16(pa, af.v, vacc[dt], 0, 0, 0);
            }
        }
    }
#pragma unroll
    for (int dt = 0; dt < 2; dt++)
#pragma unroll
        for (int r = 0; r < 16; r++) {
            int krow = wid * 32 + (r & 3) + 8 * (r >> 2) + 4 * hi;
            attcat_b[(size_t)(512 + b * 256 + krow) * 512 + h * 64 + 32 * dt + lq] = f2bf(vacc[dt][r]);
        }
}

// ---------------- residual + LayerNorm ----------------
__global__ __launch_bounds__(256) void ln_kernel(const float* __restrict__ xa,
                                                 const float* __restrict__ xv,
                                                 const float* __restrict__ proj,
                                                 const float* __restrict__ gamma,
                                                 const float* __restrict__ beta,
                                                 float* __restrict__ out) {
    const int t = blockIdx.x;
    const int tid = threadIdx.x;
    const float* x = (t < 512) ? (xa + t * 512) : (xv + (t - 512) * 512);
    const float* pp = proj + t * 512;

    float y0 = x[tid] + pp[tid];
    float y1 = x[tid + 256] + pp[tid + 256];

    __shared__ float red[4];
    const int wid = tid >> 6, lane = tid & 63;

    float s = y0 + y1;
#pragma unroll
    for (int o = 32; o >= 1; o >>= 1) s += __shfl_xor(s, o);
    if (lane == 0) red[wid] = s;
    __syncthreads();
    float mean = (red[0] + red[1] + red[2] + red[3]) * (1.f / 512.f);

    float d0 = y0 - mean, d1 = y1 - mean;
    float v = d0 * d0 + d1 * d1;
    __syncthreads();
#pragma unroll
    for (int o = 32; o >= 1; o >>= 1) v += __shfl_xor(v, o);
    if (lane == 0) red[wid] = v;
    __syncthreads();
    float var = (red[0] + red[1] + red[2] + red[3]) * (1.f / 512.f);
    float rstd = rsqrtf(var + 1e-5f);

    out[t * 512 + tid] = d0 * rstd * gamma[tid] + beta[tid];
    out[t * 512 + tid + 256] = d1 * rstd * gamma[tid + 256] + beta[tid + 256];
}

// ---------------- final scalar reduction ----------------
__global__ __launch_bounds__(512) void finalize_scalars(const float* __restrict__ coh,
                                                        const float* __restrict__ entt,
                                                        float* __restrict__ out) {
    const int tid = threadIdx.x;
    float c = coh[tid], e = entt[tid];
    const int wid = tid >> 6, lane = tid & 63;
    __shared__ float rc[8], re[8];
#pragma unroll
    for (int o = 32; o >= 1; o >>= 1) {
        c += __shfl_xor(c, o);
        e += __shfl_xor(e, o);
    }
    if (lane == 0) { rc[wid] = c; re[wid] = e; }
    __syncthreads();
    if (tid == 0) {
        float cs = 0.f, es = 0.f;
#pragma unroll
        for (int i = 0; i < 8; i++) { cs += rc[i]; es += re[i]; }
        out[524288] = cs / (512.f * 65536.f);
        out[524289] = es / 512.f;
    }
}

extern "C" void kernel_launch(void* const* d_in, const int* in_sizes, int n_in,
                              void* d_out, int out_size, void* d_ws, size_t ws_size,
                              hipStream_t stream) {
    const float* audio  = (const float*)d_in[0];
    const float* visual = (const float*)d_in[1];
    const float* Wq = (const float*)d_in[2];
    const float* bq = (const float*)d_in[3];
    const float* Wk = (const float*)d_in[4];
    const float* bk = (const float*)d_in[5];
    const float* Wv = (const float*)d_in[6];
    const float* bv = (const float*)d_in[7];
    const float* Wo = (const float*)d_in[8];
    const float* bo = (const float*)d_in[9];
    const float* We = (const float*)d_in[10];
    const float* be = (const float*)d_in[11];
    const float* gamma = (const float*)d_in[12];
    const float* beta  = (const float*)d_in[13];
    float* out = (float*)d_out;

    float* ws = (float*)d_ws;
    float* aq    = ws;                   // 262144 f32
    float* vk    = ws + 262144;
    float* vv    = ws + 524288;
    float* av    = ws + 786432;
    float* proj  = ws + 1048576;         // 524288
    float* scale = ws + 1572864;         // 512
    float* coh   = ws + 1573376;         // 512
    float* entt  = ws + 1573888;         // 512
    unsigned short* attcat_b = (unsigned short*)(ws + 1574400);  // 524288 bf16
    unsigned short* audio_b  = (unsigned short*)(ws + 1836544);  // 262144 bf16
    unsigned short* visual_b = (unsigned short*)(ws + 1967616);
    unsigned short* Wqt = (unsigned short*)(ws + 2098688);
    unsigned short* Wkt = (unsigned short*)(ws + 2229760);
    unsigned short* Wvt = (unsigned short*)(ws + 2360832);
    unsigned short* Wot = (unsigned short*)(ws + 2491904);
    unsigned short* p_t = (unsigned short*)(ws + 2622976);       // 1048576 bf16 (2MB)

    // 0) bf16 conversion + weight transposes
    hipLaunchKernelGGL(prep_bf16, dim3(16, 16, 6), dim3(256), 0, stream,
                       audio, visual, Wq, Wk, Wv, Wo,
                       audio_b, visual_b, Wqt, Wkt, Wvt, Wot);

    // 1) projections (MFMA)
    MfmaArgs g1;
    g1.A[0] = audio_b;  g1.Bt[0] = Wqt; g1.bias[0] = bq; g1.C[0] = aq;
    g1.A[1] = visual_b; g1.Bt[1] = Wkt; g1.bias[1] = bk; g1.C[1] = vk;
    g1.A[2] = visual_b; g1.Bt[2] = Wvt; g1.bias[2] = bv; g1.C[2] = vv;
    g1.A[3] = audio_b;  g1.Bt[3] = Wvt; g1.bias[3] = bv; g1.C[3] = av;
    hipLaunchKernelGGL(gemm_mfma, dim3(8, 8, 4), dim3(256), 0, stream, g1);

    // 2) per-token scalar path
    hipLaunchKernelGGL(token_scalars, dim3(512), dim3(64), 0, stream,
                       audio, visual, We, be, scale, coh, entt);

    // 3) fused attention (logits+softmax+PV+P^T AV + attn[:,7])
    hipLaunchKernelGGL(fused_attn, dim3(8, 2), dim3(512), 65536, stream,
                       aq, vk, vv, av, scale, p_t, attcat_b, out + 524290);

    // 4) output projection (MFMA): proj = attcat @ Wo + bo   (M=1024)
    MfmaArgs g2;
    for (int i = 0; i < 4; i++) { g2.A[i] = attcat_b; g2.Bt[i] = Wot; g2.bias[i] = bo; g2.C[i] = proj; }
    hipLaunchKernelGGL(gemm_mfma, dim3(8, 16, 1), dim3(256), 0, stream, g2);

    // 5) residual + LN
    hipLaunchKernelGGL(ln_kernel, dim3(1024), dim3(256), 0, stream,
                       audio, visual, proj, gamma, beta, out);

    // 6) scalars
    hipLaunchKernelGGL(finalize_scalars, dim3(1), dim3(512), 0, stream, coh, entt, out);
}

// Round 6
// 68.178 us; speedup vs baseline: 2.4892x; 1.0499x over previous
//
#include <hip/hip_runtime.h>
#include <math.h>

#define PI_F 3.14159265358979323846f

typedef __attribute__((ext_vector_type(8))) short short8v;
typedef __attribute__((ext_vector_type(4))) float f32x4;
typedef __attribute__((ext_vector_type(16))) float f32x16;

__device__ __forceinline__ unsigned short f2bf(float f) {
    unsigned int u = __float_as_uint(f);
    u += 0x7fffu + ((u >> 16) & 1u);
    return (unsigned short)(u >> 16);
}

__device__ __forceinline__ unsigned int cvtpk_bf16(float lo, float hi) {
    unsigned int r;
    asm("v_cvt_pk_bf16_f32 %0, %1, %2" : "=v"(r) : "v"(lo), "v"(hi));
    return r;
}

union W8 { unsigned int w[4]; short8v v; };

__device__ __forceinline__ void gload_lds16(const void* g, void* l) {
    __builtin_amdgcn_global_load_lds((const __attribute__((address_space(1))) unsigned int*)g,
                                     (__attribute__((address_space(3))) unsigned int*)l, 16, 0, 0);
}

// ---------------- prep (f32->bf16 + W^T) fused with token scalar path ----------------
// blocks [0,1536): prep; blocks [1536,1664): 4 waves x 1 token each
__global__ __launch_bounds__(256) void prep_tok(const float* __restrict__ audio,
                                                const float* __restrict__ visual,
                                                const float* __restrict__ Wq,
                                                const float* __restrict__ Wk,
                                                const float* __restrict__ Wv,
                                                const float* __restrict__ Wo,
                                                const float* __restrict__ We,
                                                const float* __restrict__ be,
                                                unsigned short* __restrict__ audio_b,
                                                unsigned short* __restrict__ visual_b,
                                                unsigned short* __restrict__ Wqt,
                                                unsigned short* __restrict__ Wkt,
                                                unsigned short* __restrict__ Wvt,
                                                unsigned short* __restrict__ Wot,
                                                float* __restrict__ scale,
                                                float* __restrict__ coh_tok,
                                                float* __restrict__ ent_tok) {
    __shared__ float tile[32][33];
    const int bid = blockIdx.x;
    if (bid < 1536) {
        const int z = bid >> 8;
        const int x0 = (bid & 15) * 32, y0 = ((bid >> 4) & 15) * 32;
        const int tx = threadIdx.x & 31, ty = threadIdx.x >> 5;
        if (z < 2) {
            const float* src = z ? visual : audio;
            unsigned short* dst = z ? visual_b : audio_b;
#pragma unroll
            for (int i = 0; i < 4; i++) {
                int r = y0 + ty + i * 8;
                dst[r * 512 + x0 + tx] = f2bf(src[r * 512 + x0 + tx]);
            }
        } else {
            const float* src = (z == 2) ? Wq : (z == 3) ? Wk : (z == 4) ? Wv : Wo;
            unsigned short* dst = (z == 2) ? Wqt : (z == 3) ? Wkt : (z == 4) ? Wvt : Wot;
#pragma unroll
            for (int i = 0; i < 4; i++)
                tile[ty + i * 8][tx] = src[(y0 + ty + i * 8) * 512 + x0 + tx];
            __syncthreads();
#pragma unroll
            for (int i = 0; i < 4; i++) {
                int n = x0 + ty + i * 8;
                dst[n * 512 + y0 + tx] = f2bf(tile[tx][ty + i * 8]);
            }
        }
    } else {
        const int t = (bid - 1536) * 4 + (threadIdx.x >> 6);
        const int lane = threadIdx.x & 63;
        float accA[8] = {}, accV[8] = {};
#pragma unroll
        for (int i = 0; i < 8; i++) {
            int k = i * 64 + lane;
            float wa = audio[t * 512 + k], wv = visual[t * 512 + k];
            const float* wrow = &We[k * 512];
#pragma unroll
            for (int c = 0; c < 8; c++) {
                float w = wrow[c];
                accA[c] += wa * w;
                accV[c] += wv * w;
            }
        }
#pragma unroll
        for (int c = 0; c < 8; c++) {
#pragma unroll
            for (int o = 32; o >= 1; o >>= 1) {
                accA[c] += __shfl_xor(accA[c], o);
                accV[c] += __shfl_xor(accV[c], o);
            }
        }
        if (lane == 0) {
            float pa = 1.f, pv = 1.f;
#pragma unroll
            for (int c = 0; c < 8; c++) {
                pa *= cosf((accA[c] + be[c]) * (PI_F * 0.5f));
                pv *= cosf((accV[c] + be[c]) * (PI_F * 0.5f));
            }
            float s0a = pa / (fabsf(pa) + 1e-10f);
            float s0v = pv / (fabsf(pv) + 1e-10f);
            float e = s0a * s0v;
            const float a = 0.7071f;
            float ent0 = a * e;
            float qsum = 2.f * ent0 * ent0;
            float interf = (ent0 < 0.f) ? cosf(2.f * PI_F / 65536.f) : 1.f;
            scale[t] = qsum * interf;
            coh_tok[t] = 2.f * fabsf(ent0);
            float p = (ent0 * ent0) / (qsum + 1e-10f);
            ent_tok[t] = -2.f * p * logf(p + 1e-10f);
        }
    }
}

// ---------------- bf16 MFMA GEMM: C = A @ Bt^T + bias (validated r2) ----------------
struct MfmaArgs {
    const unsigned short* A[4];
    const unsigned short* Bt[4];
    const float* bias[4];
    float* C[4];
};

__global__ __launch_bounds__(256) void gemm_mfma(MfmaArgs args) {
    const int zb = blockIdx.z;
    const unsigned short* __restrict__ A = args.A[zb];
    const unsigned short* __restrict__ Bt = args.Bt[zb];
    const float* __restrict__ bias = args.bias[zb];
    float* __restrict__ C = args.C[zb];

    const int n0 = blockIdx.x * 64;
    const int m0 = blockIdx.y * 64;

    __shared__ unsigned short As[64 * 64];
    __shared__ unsigned short Bs[64 * 64];

    const int tid = threadIdx.x;
    const int lane = tid & 63;
    const int wid = tid >> 6;
    const int wr = wid >> 1, wc = wid & 1;
    const int l15 = lane & 15;
    const int lhi = lane >> 4;

    f32x4 acc[2][2] = {};

    for (int kt = 0; kt < 8; kt++) {
        const int k0 = kt * 64;
#pragma unroll
        for (int i = 0; i < 2; i++) {
            int row = i * 32 + wid * 8 + (lane >> 3);
            int pc = lane & 7;
            int lc = pc ^ (row & 7);
            const unsigned short* gA = A + (m0 + row) * 512 + k0 + lc * 8;
            const unsigned short* gB = Bt + (n0 + row) * 512 + k0 + lc * 8;
            gload_lds16(gA, (char*)As + i * 4096 + wid * 1024);
            gload_lds16(gB, (char*)Bs + i * 4096 + wid * 1024);
        }
        __syncthreads();
#pragma unroll
        for (int ks = 0; ks < 2; ks++) {
            short8v a[2], b[2];
            const int lcr = ks * 4 + lhi;
#pragma unroll
            for (int qi = 0; qi < 2; qi++) {
                int row = wr * 32 + qi * 16 + l15;
                int pcc = lcr ^ (row & 7);
                a[qi] = *(const short8v*)((const char*)As + row * 128 + pcc * 16);
            }
#pragma unroll
            for (int nj = 0; nj < 2; nj++) {
                int row = wc * 32 + nj * 16 + l15;
                int pcc = lcr ^ (row & 7);
                b[nj] = *(const short8v*)((const char*)Bs + row * 128 + pcc * 16);
            }
#pragma unroll
            for (int qi = 0; qi < 2; qi++)
#pragma unroll
                for (int nj = 0; nj < 2; nj++)
                    acc[qi][nj] = __builtin_amdgcn_mfma_f32_16x16x32_bf16(a[qi], b[nj], acc[qi][nj], 0, 0, 0);
        }
        __syncthreads();
    }

#pragma unroll
    for (int qi = 0; qi < 2; qi++)
#pragma unroll
        for (int nj = 0; nj < 2; nj++)
#pragma unroll
            for (int r = 0; r < 4; r++) {
                int row = m0 + wr * 32 + qi * 16 + lhi * 4 + r;
                int col = n0 + wc * 32 + nj * 16 + l15;
                C[row * 512 + col] = acc[qi][nj][r] + bias[col];
            }
}

// ---------------- fused attention (r4-validated monolith) ----------------
// One block per (b,h), 512 threads = 8 waves. LDS = 64KB (Q,K staging only).
// P^T round-trips through global scratch p_t (L2-resident); intra-block RAW is
// made visible by __threadfence_block + __syncthreads (same CU/L1/L2).
__global__ __launch_bounds__(512, 2) void fused_attn(const float* __restrict__ aq,
                                                     const float* __restrict__ vk,
                                                     const float* __restrict__ vv,
                                                     const float* __restrict__ av,
                                                     const float* __restrict__ scale,
                                                     unsigned short* __restrict__ p_t,
                                                     unsigned short* __restrict__ attcat_b,
                                                     float* __restrict__ attn_last) {
    extern __shared__ char smem[];
    char* Qb = smem;            // [256][64] bf16, 128B rows, chunk-swizzled
    char* Kb = smem + 32768;

    const int h = blockIdx.x, b = blockIdx.y;
    const int tid = threadIdx.x;
    const int wid = tid >> 6;
    const int lane = tid & 63;
    const int lq = lane & 31;
    const int hi = lane >> 5;

    // ---- stage Q, K (f32 global -> bf16 LDS, swizzled) ----
    {
        int r = tid >> 1, ch = tid & 1;
        const float* qsrc = aq + (size_t)(b * 256 + r) * 512 + h * 64 + ch * 32;
        const float* ksrc = vk + (size_t)(b * 256 + r) * 512 + h * 64 + ch * 32;
#pragma unroll
        for (int i = 0; i < 4; i++) {
            float4 a0 = *(const float4*)(qsrc + i * 8);
            float4 a1 = *(const float4*)(qsrc + i * 8 + 4);
            W8 u;
            u.w[0] = cvtpk_bf16(a0.x, a0.y); u.w[1] = cvtpk_bf16(a0.z, a0.w);
            u.w[2] = cvtpk_bf16(a1.x, a1.y); u.w[3] = cvtpk_bf16(a1.z, a1.w);
            int slot = (ch * 4 + i) ^ (r & 7);
            *(short8v*)(Qb + r * 128 + (slot << 4)) = u.v;
            float4 b0 = *(const float4*)(ksrc + i * 8);
            float4 b1 = *(const float4*)(ksrc + i * 8 + 4);
            W8 vw;
            vw.w[0] = cvtpk_bf16(b0.x, b0.y); vw.w[1] = cvtpk_bf16(b0.z, b0.w);
            vw.w[2] = cvtpk_bf16(b1.x, b1.y); vw.w[3] = cvtpk_bf16(b1.z, b1.w);
            *(short8v*)(Kb + r * 128 + (slot << 4)) = vw.v;
        }
    }
    __syncthreads();

    // ---- QK^T (swapped, 32x32x16): p[t][r] = S[q=wid*32+lq][k=32t+crow(r,hi)] ----
    f32x16 p[8] = {};
    {
        short8v qf[4];
        const int qrow = wid * 32 + lq;
#pragma unroll
        for (int s = 0; s < 4; s++) {
            int slot = (2 * s + hi) ^ (qrow & 7);
            qf[s] = *(const short8v*)(Qb + qrow * 128 + (slot << 4));
        }
#pragma unroll
        for (int t = 0; t < 8; t++) {
            const int krow = t * 32 + lq;
#pragma unroll
            for (int s = 0; s < 4; s++) {
                int slot = (2 * s + hi) ^ (krow & 7);
                short8v kf = *(const short8v*)(Kb + krow * 128 + (slot << 4));
                p[t] = __builtin_amdgcn_mfma_f32_32x32x16_bf16(kf, qf[s], p[t], 0, 0, 0);
            }
        }
    }

    // ---- softmax over k (lane-local + one xor32) ----
    {
        const float sq = scale[b * 256 + wid * 32 + lq] * 0.125f;
        float mx = -1e30f;
#pragma unroll
        for (int t = 0; t < 8; t++) {
            p[t] *= sq;
#pragma unroll
            for (int r = 0; r < 16; r++) mx = fmaxf(mx, p[t][r]);
        }
        mx = fmaxf(mx, __shfl_xor(mx, 32));
        float sum = 0.f;
#pragma unroll
        for (int t = 0; t < 8; t++)
#pragma unroll
            for (int r = 0; r < 16; r++) {
                float e = __expf(p[t][r] - mx);
                p[t][r] = e;
                sum += e;
            }
        sum += __shfl_xor(sum, 32);
        float inv = 1.0f / sum;
#pragma unroll
        for (int t = 0; t < 8; t++) p[t] *= inv;
    }

    // ---- audio PV: A-frags via cvt_pk + shfl_xor(32) partner exchange ----
    f32x16 aacc[2] = {};
#pragma unroll
    for (int t = 0; t < 8; t++) {
        unsigned int c0 = cvtpk_bf16(p[t][0], p[t][1]);
        unsigned int c1 = cvtpk_bf16(p[t][2], p[t][3]);
        unsigned int c2 = cvtpk_bf16(p[t][4], p[t][5]);
        unsigned int c3 = cvtpk_bf16(p[t][6], p[t][7]);
        unsigned int e0 = (unsigned int)__shfl_xor((int)c0, 32);
        unsigned int e1 = (unsigned int)__shfl_xor((int)c1, 32);
        unsigned int e2 = (unsigned int)__shfl_xor((int)c2, 32);
        unsigned int e3 = (unsigned int)__shfl_xor((int)c3, 32);
        W8 fa0;
        fa0.w[0] = hi ? e2 : c0;
        fa0.w[1] = hi ? e3 : c1;
        fa0.w[2] = hi ? c2 : e0;
        fa0.w[3] = hi ? c3 : e1;
        unsigned int c4 = cvtpk_bf16(p[t][8], p[t][9]);
        unsigned int c5 = cvtpk_bf16(p[t][10], p[t][11]);
        unsigned int c6 = cvtpk_bf16(p[t][12], p[t][13]);
        unsigned int c7 = cvtpk_bf16(p[t][14], p[t][15]);
        unsigned int e4 = (unsigned int)__shfl_xor((int)c4, 32);
        unsigned int e5 = (unsigned int)__shfl_xor((int)c5, 32);
        unsigned int e6 = (unsigned int)__shfl_xor((int)c6, 32);
        unsigned int e7 = (unsigned int)__shfl_xor((int)c7, 32);
        W8 fa1;
        fa1.w[0] = hi ? e6 : c4;
        fa1.w[1] = hi ? e7 : c5;
        fa1.w[2] = hi ? c6 : e4;
        fa1.w[3] = hi ? c7 : e5;
#pragma unroll
        for (int dt = 0; dt < 2; dt++) {
            const float* vb0 = vv + (size_t)(b * 256 + 32 * t + 8 * hi) * 512 + h * 64 + 32 * dt + lq;
            W8 vf;
            vf.w[0] = cvtpk_bf16(vb0[0 * 512], vb0[1 * 512]);
            vf.w[1] = cvtpk_bf16(vb0[2 * 512], vb0[3 * 512]);
            vf.w[2] = cvtpk_bf16(vb0[4 * 512], vb0[5 * 512]);
            vf.w[3] = cvtpk_bf16(vb0[6 * 512], vb0[7 * 512]);
            aacc[dt] = __builtin_amdgcn_mfma_f32_32x32x16_bf16(fa0.v, vf.v, aacc[dt], 0, 0, 0);
            const float* vb1 = vb0 + 16 * 512;
            W8 vg;
            vg.w[0] = cvtpk_bf16(vb1[0 * 512], vb1[1 * 512]);
            vg.w[1] = cvtpk_bf16(vb1[2 * 512], vb1[3 * 512]);
            vg.w[2] = cvtpk_bf16(vb1[4 * 512], vb1[5 * 512]);
            vg.w[3] = cvtpk_bf16(vb1[6 * 512], vb1[7 * 512]);
            aacc[dt] = __builtin_amdgcn_mfma_f32_32x32x16_bf16(fa1.v, vg.v, aacc[dt], 0, 0, 0);
        }
    }
#pragma unroll
    for (int dt = 0; dt < 2; dt++)
#pragma unroll
        for (int r = 0; r < 16; r++) {
            int qrow = wid * 32 + (r & 3) + 8 * (r >> 2) + 4 * hi;
            attcat_b[(size_t)(b * 256 + qrow) * 512 + h * 64 + 32 * dt + lq] = f2bf(aacc[dt][r]);
        }

    // ---- write P^T (bf16) to global scratch: p_t[(b*8+h)][k][q] ----
    {
        unsigned short* pdst = p_t + (size_t)(b * 8 + h) * 65536;
#pragma unroll
        for (int t = 0; t < 8; t++)
#pragma unroll
            for (int r = 0; r < 16; r++) {
                int k = 32 * t + (r & 3) + 8 * (r >> 2) + 4 * hi;
                pdst[k * 256 + wid * 32 + lq] = f2bf(p[t][r]);
            }
    }
    __threadfence_block();
    __syncthreads();  // Q/K reads done; P^T writes drained to L2

    // ---- attn[:, 7] output (f32), per-wave LDS transpose tile ----
    if (h == 7) {
        float* tile = (float*)smem + (size_t)wid * (32 * 33);
        const int q2 = lane >> 1, koff = (lane & 1) * 16;
#pragma unroll
        for (int t = 0; t < 8; t++) {
#pragma unroll
            for (int r = 0; r < 16; r++)
                tile[lq * 33 + ((r & 3) + 8 * (r >> 2) + 4 * hi)] = p[t][r];
            __syncthreads();
            float* orow = attn_last + (size_t)(b * 256 + wid * 32 + q2) * 256 + 32 * t + koff;
#pragma unroll
            for (int j = 0; j < 16; j++) orow[j] = tile[q2 * 33 + koff + j];
            __syncthreads();
        }
    }

    // ---- visual: out[k][d] = sum_q P^T[k][q] AV[q][d] ----
    f32x16 vacc[2] = {};
    {
        const int krow = wid * 32 + lq;
        const unsigned short* prow = p_t + (size_t)(b * 8 + h) * 65536 + (size_t)krow * 256;
#pragma unroll
        for (int u = 0; u < 16; u++) {
            short8v pa = *(const short8v*)(prow + 16 * u + 8 * hi);
#pragma unroll
            for (int dt = 0; dt < 2; dt++) {
                const float* ab = av + (size_t)(b * 256 + 16 * u + 8 * hi) * 512 + h * 64 + 32 * dt + lq;
                W8 af;
                af.w[0] = cvtpk_bf16(ab[0 * 512], ab[1 * 512]);
                af.w[1] = cvtpk_bf16(ab[2 * 512], ab[3 * 512]);
                af.w[2] = cvtpk_bf16(ab[4 * 512], ab[5 * 512]);
                af.w[3] = cvtpk_bf16(ab[6 * 512], ab[7 * 512]);
                vacc[dt] = __builtin_amdgcn_mfma_f32_32x32x16_bf16(pa, af.v, vacc[dt], 0, 0, 0);
            }
        }
    }
#pragma unroll
    for (int dt = 0; dt < 2; dt++)
#pragma unroll
        for (int r = 0; r < 16; r++) {
            int krow = wid * 32 + (r & 3) + 8 * (r >> 2) + 4 * hi;
            attcat_b[(size_t)(512 + b * 256 + krow) * 512 + h * 64 + 32 * dt + lq] = f2bf(vacc[dt][r]);
        }
}

// ---------------- residual + LayerNorm + final scalars ----------------
__global__ __launch_bounds__(256) void ln_final(const float* __restrict__ xa,
                                                const float* __restrict__ xv,
                                                const float* __restrict__ proj,
                                                const float* __restrict__ gamma,
                                                const float* __restrict__ beta,
                                                const float* __restrict__ coh,
                                                const float* __restrict__ entt,
                                                float* __restrict__ out) {
    __shared__ float red[4], red2[4];
    const int t = blockIdx.x;
    const int tid = threadIdx.x;
    const int wid = tid >> 6, lane = tid & 63;

    if (t < 1024) {
        const float* x = (t < 512) ? (xa + t * 512) : (xv + (t - 512) * 512);
        const float* pp = proj + t * 512;

        float y0 = x[tid] + pp[tid];
        float y1 = x[tid + 256] + pp[tid + 256];

        float s = y0 + y1;
#pragma unroll
        for (int o = 32; o >= 1; o >>= 1) s += __shfl_xor(s, o);
        if (lane == 0) red[wid] = s;
        __syncthreads();
        float mean = (red[0] + red[1] + red[2] + red[3]) * (1.f / 512.f);

        float d0 = y0 - mean, d1 = y1 - mean;
        float v = d0 * d0 + d1 * d1;
        __syncthreads();
#pragma unroll
        for (int o = 32; o >= 1; o >>= 1) v += __shfl_xor(v, o);
        if (lane == 0) red[wid] = v;
        __syncthreads();
        float var = (red[0] + red[1] + red[2] + red[3]) * (1.f / 512.f);
        float rstd = rsqrtf(var + 1e-5f);

        out[t * 512 + tid] = d0 * rstd * gamma[tid] + beta[tid];
        out[t * 512 + tid + 256] = d1 * rstd * gamma[tid + 256] + beta[tid + 256];
    } else {
        float c = coh[tid] + coh[tid + 256];
        float e = entt[tid] + entt[tid + 256];
#pragma unroll
        for (int o = 32; o >= 1; o >>= 1) {
            c += __shfl_xor(c, o);
            e += __shfl_xor(e, o);
        }
        if (lane == 0) { red[wid] = c; red2[wid] = e; }
        __syncthreads();
        if (tid == 0) {
            float cs = red[0] + red[1] + red[2] + red[3];
            float es = red2[0] + red2[1] + red2[2] + red2[3];
            out[524288] = cs / (512.f * 65536.f);
            out[524289] = es / 512.f;
        }
    }
}

extern "C" void kernel_launch(void* const* d_in, const int* in_sizes, int n_in,
                              void* d_out, int out_size, void* d_ws, size_t ws_size,
                              hipStream_t stream) {
    const float* audio  = (const float*)d_in[0];
    const float* visual = (const float*)d_in[1];
    const float* Wq = (const float*)d_in[2];
    const float* bq = (const float*)d_in[3];
    const float* Wk = (const float*)d_in[4];
    const float* bk = (const float*)d_in[5];
    const float* Wv = (const float*)d_in[6];
    const float* bv = (const float*)d_in[7];
    const float* Wo = (const float*)d_in[8];
    const float* bo = (const float*)d_in[9];
    const float* We = (const float*)d_in[10];
    const float* be = (const float*)d_in[11];
    const float* gamma = (const float*)d_in[12];
    const float* beta  = (const float*)d_in[13];
    float* out = (float*)d_out;

    float* ws = (float*)d_ws;
    float* aq    = ws;                   // 262144 f32
    float* vk    = ws + 262144;
    float* vv    = ws + 524288;
    float* av    = ws + 786432;
    float* proj  = ws + 1048576;         // 524288
    float* scale = ws + 1572864;         // 512
    float* coh   = ws + 1573376;         // 512
    float* entt  = ws + 1573888;         // 512
    unsigned short* attcat_b = (unsigned short*)(ws + 1574400);  // 524288 bf16
    unsigned short* audio_b  = (unsigned short*)(ws + 1836544);  // 262144 bf16
    unsigned short* visual_b = (unsigned short*)(ws + 1967616);
    unsigned short* Wqt = (unsigned short*)(ws + 2098688);
    unsigned short* Wkt = (unsigned short*)(ws + 2229760);
    unsigned short* Wvt = (unsigned short*)(ws + 2360832);
    unsigned short* Wot = (unsigned short*)(ws + 2491904);
    unsigned short* p_t = (unsigned short*)(ws + 2622976);       // 1048576 bf16 (2MB)

    // 0) prep (bf16 + W^T) + token scalar path, one launch
    hipLaunchKernelGGL(prep_tok, dim3(1664), dim3(256), 0, stream,
                       audio, visual, Wq, Wk, Wv, Wo, We, be,
                       audio_b, visual_b, Wqt, Wkt, Wvt, Wot,
                       scale, coh, entt);

    // 1) projections (MFMA)
    MfmaArgs g1;
    g1.A[0] = audio_b;  g1.Bt[0] = Wqt; g1.bias[0] = bq; g1.C[0] = aq;
    g1.A[1] = visual_b; g1.Bt[1] = Wkt; g1.bias[1] = bk; g1.C[1] = vk;
    g1.A[2] = visual_b; g1.Bt[2] = Wvt; g1.bias[2] = bv; g1.C[2] = vv;
    g1.A[3] = audio_b;  g1.Bt[3] = Wvt; g1.bias[3] = bv; g1.C[3] = av;
    hipLaunchKernelGGL(gemm_mfma, dim3(8, 8, 4), dim3(256), 0, stream, g1);

    // 2) fused attention (r4-validated): QK^T + softmax + PV + P^T AV + attn[:,7]
    hipLaunchKernelGGL(fused_attn, dim3(8, 2), dim3(512), 65536, stream,
                       aq, vk, vv, av, scale, p_t, attcat_b, out + 524290);

    // 3) output projection (MFMA): proj = attcat @ Wo + bo   (M=1024)
    MfmaArgs g2;
    for (int i = 0; i < 4; i++) { g2.A[i] = attcat_b; g2.Bt[i] = Wot; g2.bias[i] = bo; g2.C[i] = proj; }
    hipLaunchKernelGGL(gemm_mfma, dim3(8, 16, 1), dim3(256), 0, stream, g2);

    // 4) residual + LN + scalars
    hipLaunchKernelGGL(ln_final, dim3(1025), dim3(256), 0, stream,
                       audio, visual, proj, gamma, beta, coh, entt, out);
}